// Round 1
// baseline (651.659 us; speedup 1.0000x reference)
//
#include <hip/hip_runtime.h>
#include <cmath>

// INGP hashgrid encode: out[n, l*2+f] = trilinear-interp of hashed table entries.
// N=524288 points, L=16 levels, F=2, T=2^19 entries/level.

constexpr int LVLS = 16;
constexpr unsigned TBL = 1u << 19;
constexpr unsigned TMASK = TBL - 1u;
constexpr unsigned P1 = 2654435761u;
constexpr unsigned P2 = 805459861u;

struct ResArr { float r[LVLS]; };

__global__ __launch_bounds__(256, 8) void ingp_fwd(
    const float* __restrict__ pts,
    const float* __restrict__ tables,
    float* __restrict__ out,
    ResArr ra, int npts)
{
    // Broadcast per-level resolutions through LDS (lane-dynamic index on a
    // by-value kernel arg would otherwise go to scratch).
    __shared__ float s_res[LVLS];
    if (threadIdx.x < LVLS) s_res[threadIdx.x] = ra.r[threadIdx.x];
    __syncthreads();

    int tid = blockIdx.x * blockDim.x + threadIdx.x;
    int point = tid >> 4;      // 16 levels per point; lane-consecutive levels
    int lvl = tid & 15;
    if (point >= npts) return;

    // 16 lanes share one point -> L1 broadcast.
    float px = pts[point * 3 + 0];
    float py = pts[point * 3 + 1];
    float pz = pts[point * 3 + 2];
    // x = (p - VMIN) / (VMAX - VMIN) = (p + 1) * 0.5 ; exact same f32 rounding
    float x = (px + 1.0f) * 0.5f;
    float y = (py + 1.0f) * 0.5f;
    float z = (pz + 1.0f) * 0.5f;

    float r = s_res[lvl];
    float posx = x * r, posy = y * r, posz = z * r;
    float fx = floorf(posx), fy = floorf(posy), fz = floorf(posz);
    float wx = posx - fx, wy = posy - fy, wz = posz - fz;

    unsigned ix = (unsigned)fx, iy = (unsigned)fy, iz = (unsigned)fz;
    // hash components; (i+1)*P == i*P + P mod 2^32
    unsigned hx0 = ix,        hx1 = ix + 1u;
    unsigned hy0 = iy * P1,   hy1 = hy0 + P1;
    unsigned hz0 = iz * P2,   hz1 = hz0 + P2;

    const float2* __restrict__ tab =
        (const float2*)tables + (size_t)lvl * (size_t)TBL;

    // Corner order matches CORNERS: c = (i,j,k), i outermost (x dim).
    unsigned i000 = (hx0 ^ hy0 ^ hz0) & TMASK;
    unsigned i001 = (hx0 ^ hy0 ^ hz1) & TMASK;
    unsigned i010 = (hx0 ^ hy1 ^ hz0) & TMASK;
    unsigned i011 = (hx0 ^ hy1 ^ hz1) & TMASK;
    unsigned i100 = (hx1 ^ hy0 ^ hz0) & TMASK;
    unsigned i101 = (hx1 ^ hy0 ^ hz1) & TMASK;
    unsigned i110 = (hx1 ^ hy1 ^ hz0) & TMASK;
    unsigned i111 = (hx1 ^ hy1 ^ hz1) & TMASK;

    // 8 independent gathers — issue all before use for latency overlap.
    float2 v000 = tab[i000];
    float2 v001 = tab[i001];
    float2 v010 = tab[i010];
    float2 v011 = tab[i011];
    float2 v100 = tab[i100];
    float2 v101 = tab[i101];
    float2 v110 = tab[i110];
    float2 v111 = tab[i111];

    float ox = 1.0f - wx, oy = 1.0f - wy, oz = 1.0f - wz;
    // weight product order matches .prod(-1): (d0*d1)*d2
    float w000 = (ox * oy) * oz;
    float w001 = (ox * oy) * wz;
    float w010 = (ox * wy) * oz;
    float w011 = (ox * wy) * wz;
    float w100 = (wx * oy) * oz;
    float w101 = (wx * oy) * wz;
    float w110 = (wx * wy) * oz;
    float w111 = (wx * wy) * wz;

    // einsum over corners, ascending corner index
    float f0 = w000 * v000.x;
    float f1 = w000 * v000.y;
    f0 += w001 * v001.x;  f1 += w001 * v001.y;
    f0 += w010 * v010.x;  f1 += w010 * v010.y;
    f0 += w011 * v011.x;  f1 += w011 * v011.y;
    f0 += w100 * v100.x;  f1 += w100 * v100.y;
    f0 += w101 * v101.x;  f1 += w101 * v101.y;
    f0 += w110 * v110.x;  f1 += w110 * v110.y;
    f0 += w111 * v111.x;  f1 += w111 * v111.y;

    // Lane-consecutive (point,lvl) -> contiguous 512B per wave store.
    ((float2*)out)[(size_t)point * LVLS + lvl] = make_float2(f0, f1);
}

extern "C" void kernel_launch(void* const* d_in, const int* in_sizes, int n_in,
                              void* d_out, int out_size, void* d_ws, size_t ws_size,
                              hipStream_t stream) {
    const float* pts    = (const float*)d_in[0];
    const float* tables = (const float*)d_in[1];
    float* out = (float*)d_out;
    int npts = in_sizes[0] / 3;

    // Replicate numpy's RES computation bitwise in float64:
    // GROWTH = exp((log(2048) - log(16)) / 15); RES = floor(16 * GROWTH**l)
    ResArr ra;
    double growth = exp((log(2048.0) - log(16.0)) / 15.0);
    for (int l = 0; l < LVLS; ++l)
        ra.r[l] = (float)floor(16.0 * pow(growth, (double)l));

    long long total = (long long)npts * LVLS;
    int block = 256;
    int grid = (int)((total + block - 1) / block);
    hipLaunchKernelGGL(ingp_fwd, dim3(grid), dim3(block), 0, stream,
                       pts, tables, out, ra, npts);
}

// Round 2
// 387.361 us; speedup vs baseline: 1.6823x; 1.6823x over previous
//
#include <hip/hip_runtime.h>
#include <cmath>

// INGP hashgrid encode, XCD-partitioned:
//   level = blockIdx%8 (+8 for second half of grid) -> each XCD's 4 MiB L2
//   holds ~one 4 MiB level table -> gathers hit L2 instead of L3/HBM.
//   Gather writes level-major to ws (coalesced); transpose kernel produces
//   the [N, L*F] layout with coalesced stores via an LDS tile.

constexpr int LVLS = 16;
constexpr unsigned TBL = 1u << 19;
constexpr unsigned TMASK = TBL - 1u;
constexpr unsigned P1 = 2654435761u;
constexpr unsigned P2 = 805459861u;
constexpr int PTS_PER_BLOCK = 512;   // 256 threads x 2 points

struct ResArr { float r[LVLS]; };

template<bool USE_WS>
__global__ __launch_bounds__(256) void ingp_gather(
    const float* __restrict__ pts,
    const float* __restrict__ tables,
    float2* __restrict__ dst,     // USE_WS: [L][N] float2 ; else [N][L] float2
    ResArr ra, int npts, int bpl) // bpl = blocks per level
{
    __shared__ float s_res[LVLS];
    if (threadIdx.x < LVLS) s_res[threadIdx.x] = ra.r[threadIdx.x];
    __syncthreads();

    int b = blockIdx.x;
    int phase_blocks = 8 * bpl;                  // blocks covering levels 0..7
    int lvl = (b & 7) + 8 * (b / phase_blocks);  // XCD (b%8) pinned to one level per phase
    int q = (b % phase_blocks) >> 3;             // block index within level
    int t = threadIdx.x;

    float r = s_res[lvl];
    const float2* __restrict__ tab = (const float2*)tables + (size_t)lvl * TBL;

    int p[2];
    p[0] = q * PTS_PER_BLOCK + t;
    p[1] = p[0] + 256;

    unsigned idx[2][8];
    float w[2][8];
    bool valid[2];

    #pragma unroll
    for (int s = 0; s < 2; ++s) {
        valid[s] = p[s] < npts;
        int pp = valid[s] ? p[s] : 0;
        float px = pts[pp * 3 + 0];
        float py = pts[pp * 3 + 1];
        float pz = pts[pp * 3 + 2];
        float x = (px + 1.0f) * 0.5f;
        float y = (py + 1.0f) * 0.5f;
        float z = (pz + 1.0f) * 0.5f;
        float posx = x * r, posy = y * r, posz = z * r;
        float fx = floorf(posx), fy = floorf(posy), fz = floorf(posz);
        float wx = posx - fx, wy = posy - fy, wz = posz - fz;
        unsigned ix = (unsigned)fx, iy = (unsigned)fy, iz = (unsigned)fz;
        unsigned hx0 = ix,      hx1 = ix + 1u;
        unsigned hy0 = iy * P1, hy1 = hy0 + P1;
        unsigned hz0 = iz * P2, hz1 = hz0 + P2;
        idx[s][0] = (hx0 ^ hy0 ^ hz0) & TMASK;
        idx[s][1] = (hx0 ^ hy0 ^ hz1) & TMASK;
        idx[s][2] = (hx0 ^ hy1 ^ hz0) & TMASK;
        idx[s][3] = (hx0 ^ hy1 ^ hz1) & TMASK;
        idx[s][4] = (hx1 ^ hy0 ^ hz0) & TMASK;
        idx[s][5] = (hx1 ^ hy0 ^ hz1) & TMASK;
        idx[s][6] = (hx1 ^ hy1 ^ hz0) & TMASK;
        idx[s][7] = (hx1 ^ hy1 ^ hz1) & TMASK;
        float ox = 1.0f - wx, oy = 1.0f - wy, oz = 1.0f - wz;
        w[s][0] = (ox * oy) * oz;
        w[s][1] = (ox * oy) * wz;
        w[s][2] = (ox * wy) * oz;
        w[s][3] = (ox * wy) * wz;
        w[s][4] = (wx * oy) * oz;
        w[s][5] = (wx * oy) * wz;
        w[s][6] = (wx * wy) * oz;
        w[s][7] = (wx * wy) * wz;
    }

    // Issue all 16 independent gathers before any use (latency overlap).
    float2 v[2][8];
    #pragma unroll
    for (int s = 0; s < 2; ++s)
        #pragma unroll
        for (int c = 0; c < 8; ++c)
            v[s][c] = tab[idx[s][c]];

    #pragma unroll
    for (int s = 0; s < 2; ++s) {
        float f0 = w[s][0] * v[s][0].x;
        float f1 = w[s][0] * v[s][0].y;
        #pragma unroll
        for (int c = 1; c < 8; ++c) {
            f0 += w[s][c] * v[s][c].x;
            f1 += w[s][c] * v[s][c].y;
        }
        if (valid[s]) {
            if (USE_WS)
                dst[(size_t)lvl * npts + p[s]] = make_float2(f0, f1);   // coalesced
            else
                dst[(size_t)p[s] * LVLS + lvl] = make_float2(f0, f1);   // strided fallback
        }
    }
}

// ws [L][N] float2  ->  out [N][L] float2, all-coalesced via LDS tile.
__global__ __launch_bounds__(256) void ingp_transpose(
    const float2* __restrict__ ws, float4* __restrict__ out, int npts)
{
    __shared__ float2 a[LVLS][258];   // 258 stride: 2-way-max LDS banks (free)
    int base = blockIdx.x * 256;
    int t = threadIdx.x;

    #pragma unroll
    for (int l = 0; l < LVLS; ++l) {
        int pp = base + t;
        a[l][t] = (pp < npts) ? ws[(size_t)l * npts + pp] : make_float2(0.f, 0.f);
    }
    __syncthreads();

    int j = t & 7;          // which float4 of the point's 128B row
    int pl = t >> 3;        // point within tile (0..31), advances by 32
    #pragma unroll
    for (int it = 0; it < 8; ++it) {
        int pt = pl + it * 32;
        if (base + pt < npts) {
            float2 u = a[2 * j][pt];
            float2 v = a[2 * j + 1][pt];
            out[(size_t)(base + pt) * 8 + j] = make_float4(u.x, u.y, v.x, v.y);
        }
    }
}

extern "C" void kernel_launch(void* const* d_in, const int* in_sizes, int n_in,
                              void* d_out, int out_size, void* d_ws, size_t ws_size,
                              hipStream_t stream) {
    const float* pts    = (const float*)d_in[0];
    const float* tables = (const float*)d_in[1];
    int npts = in_sizes[0] / 3;

    // numpy-bitwise RES: GROWTH = exp((log(2048)-log(16))/15); floor(16*G**l)
    ResArr ra;
    double growth = exp((log(2048.0) - log(16.0)) / 15.0);
    for (int l = 0; l < LVLS; ++l)
        ra.r[l] = (float)floor(16.0 * pow(growth, (double)l));

    int bpl = (npts + PTS_PER_BLOCK - 1) / PTS_PER_BLOCK;   // blocks per level
    int grid = LVLS * bpl;

    size_t ws_needed = (size_t)LVLS * npts * sizeof(float2);
    bool use_ws = ws_size >= ws_needed;

    if (use_ws) {
        float2* ws = (float2*)d_ws;
        hipLaunchKernelGGL(ingp_gather<true>, dim3(grid), dim3(256), 0, stream,
                           pts, tables, ws, ra, npts, bpl);
        hipLaunchKernelGGL(ingp_transpose, dim3((npts + 255) / 256), dim3(256), 0, stream,
                           ws, (float4*)d_out, npts);
    } else {
        hipLaunchKernelGGL(ingp_gather<false>, dim3(grid), dim3(256), 0, stream,
                           pts, tables, (float2*)d_out, ra, npts, bpl);
    }
}

// Round 3
// 382.148 us; speedup vs baseline: 1.7053x; 1.0136x over previous
//
#include <hip/hip_runtime.h>
#include <cmath>

// INGP hashgrid encode, XCD-partitioned + nontemporal streaming.
//   level pinned per XCD (blockIdx%8), phase1 lvl=k, phase2 lvl=15-k
//   (balances per-XCD cost: cheap coarse levels pair with expensive fine).
//   Point loads and ws stores are nontemporal so the XCD's 4MiB L2 holds
//   only the pinned 4MiB table -> higher gather hit rate -> lower latency.

constexpr int LVLS = 16;
constexpr unsigned TBL = 1u << 19;
constexpr unsigned TMASK = TBL - 1u;
constexpr unsigned P1 = 2654435761u;
constexpr unsigned P2 = 805459861u;
constexpr int PTS_PER_BLOCK = 512;   // 256 threads x 2 points

typedef float vf2 __attribute__((ext_vector_type(2)));
typedef float vf4 __attribute__((ext_vector_type(4)));

struct ResArr { float r[LVLS]; };

template<bool USE_WS>
__global__ __launch_bounds__(256) void ingp_gather(
    const float* __restrict__ pts,
    const float* __restrict__ tables,
    float2* __restrict__ dst,     // USE_WS: [L][N] float2 ; else [N][L] float2
    ResArr ra, int npts, int bpl) // bpl = blocks per level
{
    __shared__ float s_res[LVLS];
    if (threadIdx.x < LVLS) s_res[threadIdx.x] = ra.r[threadIdx.x];
    __syncthreads();

    int b = blockIdx.x;
    int phase_blocks = 8 * bpl;
    int xcd = b & 7;
    int phase = b / phase_blocks;
    int lvl = phase == 0 ? xcd : 15 - xcd;   // balanced pairing (k, 15-k)
    int q = (b % phase_blocks) >> 3;
    int t = threadIdx.x;

    float r = s_res[lvl];
    const float2* __restrict__ tab = (const float2*)tables + (size_t)lvl * TBL;

    int p[2];
    p[0] = q * PTS_PER_BLOCK + t;
    p[1] = p[0] + 256;

    unsigned idx[2][8];
    float w[2][8];
    bool valid[2];

    #pragma unroll
    for (int s = 0; s < 2; ++s) {
        valid[s] = p[s] < npts;
        int pp = valid[s] ? p[s] : 0;
        // nontemporal: streamed once per level-queue, don't cache in L2
        float px = __builtin_nontemporal_load(pts + pp * 3 + 0);
        float py = __builtin_nontemporal_load(pts + pp * 3 + 1);
        float pz = __builtin_nontemporal_load(pts + pp * 3 + 2);
        float x = (px + 1.0f) * 0.5f;
        float y = (py + 1.0f) * 0.5f;
        float z = (pz + 1.0f) * 0.5f;
        float posx = x * r, posy = y * r, posz = z * r;
        float fx = floorf(posx), fy = floorf(posy), fz = floorf(posz);
        float wx = posx - fx, wy = posy - fy, wz = posz - fz;
        unsigned ix = (unsigned)fx, iy = (unsigned)fy, iz = (unsigned)fz;
        unsigned hx0 = ix,      hx1 = ix + 1u;
        unsigned hy0 = iy * P1, hy1 = hy0 + P1;
        unsigned hz0 = iz * P2, hz1 = hz0 + P2;
        idx[s][0] = (hx0 ^ hy0 ^ hz0) & TMASK;
        idx[s][1] = (hx0 ^ hy0 ^ hz1) & TMASK;
        idx[s][2] = (hx0 ^ hy1 ^ hz0) & TMASK;
        idx[s][3] = (hx0 ^ hy1 ^ hz1) & TMASK;
        idx[s][4] = (hx1 ^ hy0 ^ hz0) & TMASK;
        idx[s][5] = (hx1 ^ hy0 ^ hz1) & TMASK;
        idx[s][6] = (hx1 ^ hy1 ^ hz0) & TMASK;
        idx[s][7] = (hx1 ^ hy1 ^ hz1) & TMASK;
        float ox = 1.0f - wx, oy = 1.0f - wy, oz = 1.0f - wz;
        w[s][0] = (ox * oy) * oz;
        w[s][1] = (ox * oy) * wz;
        w[s][2] = (ox * wy) * oz;
        w[s][3] = (ox * wy) * wz;
        w[s][4] = (wx * oy) * oz;
        w[s][5] = (wx * oy) * wz;
        w[s][6] = (wx * wy) * oz;
        w[s][7] = (wx * wy) * wz;
    }

    // Issue all 16 independent gathers before any use (latency overlap).
    float2 v[2][8];
    #pragma unroll
    for (int s = 0; s < 2; ++s)
        #pragma unroll
        for (int c = 0; c < 8; ++c)
            v[s][c] = tab[idx[s][c]];

    #pragma unroll
    for (int s = 0; s < 2; ++s) {
        float f0 = w[s][0] * v[s][0].x;
        float f1 = w[s][0] * v[s][0].y;
        #pragma unroll
        for (int c = 1; c < 8; ++c) {
            f0 += w[s][c] * v[s][c].x;
            f1 += w[s][c] * v[s][c].y;
        }
        if (valid[s]) {
            vf2 o; o.x = f0; o.y = f1;
            if (USE_WS)   // coalesced, streaming (read once by transpose)
                __builtin_nontemporal_store(o, (vf2*)(dst + (size_t)lvl * npts + p[s]));
            else
                dst[(size_t)p[s] * LVLS + lvl] = make_float2(f0, f1);
        }
    }
}

// ws [L][N] float2  ->  out [N][L] float2, all-coalesced via LDS tile.
__global__ __launch_bounds__(256) void ingp_transpose(
    const float2* __restrict__ ws, float4* __restrict__ out, int npts)
{
    __shared__ float2 a[LVLS][258];
    int base = blockIdx.x * 256;
    int t = threadIdx.x;

    #pragma unroll
    for (int l = 0; l < LVLS; ++l) {
        int pp = base + t;
        float2 val = make_float2(0.f, 0.f);
        if (pp < npts) {
            vf2 v = __builtin_nontemporal_load((const vf2*)(ws + (size_t)l * npts + pp));
            val = make_float2(v.x, v.y);
        }
        a[l][t] = val;
    }
    __syncthreads();

    int j = t & 7;          // which float4 of the point's 128B row
    int pl = t >> 3;        // point within tile, advances by 32
    #pragma unroll
    for (int it = 0; it < 8; ++it) {
        int pt = pl + it * 32;
        if (base + pt < npts) {
            float2 u = a[2 * j][pt];
            float2 v = a[2 * j + 1][pt];
            vf4 o; o.x = u.x; o.y = u.y; o.z = v.x; o.w = v.y;
            __builtin_nontemporal_store(o, (vf4*)(out + (size_t)(base + pt) * 8 + j));
        }
    }
}

extern "C" void kernel_launch(void* const* d_in, const int* in_sizes, int n_in,
                              void* d_out, int out_size, void* d_ws, size_t ws_size,
                              hipStream_t stream) {
    const float* pts    = (const float*)d_in[0];
    const float* tables = (const float*)d_in[1];
    int npts = in_sizes[0] / 3;

    // numpy-bitwise RES: GROWTH = exp((log(2048)-log(16))/15); floor(16*G**l)
    ResArr ra;
    double growth = exp((log(2048.0) - log(16.0)) / 15.0);
    for (int l = 0; l < LVLS; ++l)
        ra.r[l] = (float)floor(16.0 * pow(growth, (double)l));

    int bpl = (npts + PTS_PER_BLOCK - 1) / PTS_PER_BLOCK;
    int grid = LVLS * bpl;

    size_t ws_needed = (size_t)LVLS * npts * sizeof(float2);
    bool use_ws = ws_size >= ws_needed;

    if (use_ws) {
        float2* ws = (float2*)d_ws;
        hipLaunchKernelGGL(ingp_gather<true>, dim3(grid), dim3(256), 0, stream,
                           pts, tables, ws, ra, npts, bpl);
        hipLaunchKernelGGL(ingp_transpose, dim3((npts + 255) / 256), dim3(256), 0, stream,
                           ws, (float4*)d_out, npts);
    } else {
        hipLaunchKernelGGL(ingp_gather<false>, dim3(grid), dim3(256), 0, stream,
                           pts, tables, (float2*)d_out, ra, npts, bpl);
    }
}